// Round 1
// baseline (70.229 us; speedup 1.0000x reference)
//
#include <hip/hip_runtime.h>
#include <hip/hip_bf16.h>

typedef __attribute__((ext_vector_type(8))) short bf16x8;
typedef __attribute__((ext_vector_type(16))) float f32x16;

#define NN 16
#define CC 128
#define KK 128
#define HH 56
#define WW 56

__device__ __forceinline__ unsigned short f2bf(float f) {
  unsigned int u = __builtin_bit_cast(unsigned int, f);
  u += 0x7FFFu + ((u >> 16) & 1u);
  return (unsigned short)(u >> 16);
}

// K1: kernel (K,C,3,3) f32 -> w_t[rs][k][c] bf16   (rs = r*3+s)
__global__ void wtrans_kernel(const float* __restrict__ kin,
                              unsigned short* __restrict__ wt) {
  int idx = blockIdx.x * 256 + threadIdx.x;  // 0 .. 147455, exact
  int rs = idx % 9;
  int kc = idx / 9;
  int c = kc % CC;
  int k = kc / CC;
  wt[(rs * KK + k) * CC + c] = f2bf(kin[idx]);
}

// K2: direct 3x3 conv as implicit GEMM, bf16 MFMA 32x32x16.
// Block: 256 thr (4 waves). Output tile: 128 k x (4 rows x 56 w).
// Spatial fragment = 32 positions = 4 rows x 8 w. 7 sfrags per block.
// Wave (kp, sh): k-range kp*64..+63 (2 kfrags), sfrags sh? {4,5,6} : {0,1,2,3}.
// LDS: x staged [6 rows][58 w][64 c] bf16, swizzled, two 64-channel phases.
__global__ __launch_bounds__(256, 1) void conv_kernel(
    const float* __restrict__ x, const unsigned short* __restrict__ wt,
    float* __restrict__ out) {
  __shared__ __align__(16) unsigned char xs[6 * 58 * 128];  // 43.5 KB

  const int tid = threadIdx.x;
  const int lane = tid & 63;
  const int wv = tid >> 6;
  const int bh = blockIdx.x;  // 0..13
  const int n = blockIdx.y;   // 0..15
  const int r0 = bh * 4;

  const int p = lane & 31;   // spatial position within fragment
  const int dr = p >> 3;     // 0..3 row offset
  const int dw = p & 7;      // 0..7 col offset
  const int hi = lane >> 5;  // k-dim half

  const int kp = wv >> 1;       // 0,1 : k-pair group
  const int sh = wv & 1;        // spatial half
  const int k0 = kp * 64;
  const int s0 = sh * 4;        // first sfrag
  const int ns = sh ? 3 : 4;    // #sfrags for this wave

  f32x16 acc[2][4] = {};

  for (int ch = 0; ch < 2; ++ch) {
    if (ch) __syncthreads();
    // ---- stage x[n][ch*64 .. +63][r0-1 .. r0+4][-1 .. 56] -> LDS bf16 ----
    // 192 wave-tasks: (6 rows) x (32 channel-pairs); lanes cover w.
#pragma unroll 8
    for (int t = wv; t < 192; t += 4) {
      int lr = t >> 5;   // 0..5 local row
      int cp = t & 31;   // channel pair
      int gh = r0 - 1 + lr;
      int gw = lane - 1;
      int cg = ch * 64 + cp * 2;
      bool valid = (gh >= 0) && (gh < HH) && (gw >= 0) && (gw < WW) && (lane < 58);
      const float* xp = x + ((size_t)n * CC + cg) * (HH * WW) + gh * WW + gw;
      float v0 = valid ? xp[0] : 0.f;
      float v1 = valid ? xp[HH * WW] : 0.f;
      if (lane < 58) {
        unsigned int pr = (unsigned int)f2bf(v0) | ((unsigned int)f2bf(v1) << 16);
        int rec = lr * 58 + lane;
        int slot = (cp >> 2) ^ (lane & 7);  // XOR swizzle (T2)
        *(unsigned int*)(xs + (rec << 7) + (slot << 4) + ((cp & 3) << 2)) = pr;
      }
    }
    __syncthreads();

    // ---- GEMM over this channel half: 9 rs x 4 csteps of K=16 ----
    const unsigned short* wpc = wt + (size_t)(k0 + p) * CC + ch * 64 + hi * 8;
    for (int rs = 0; rs < 9; ++rs) {
      const int fr = rs / 3;
      const int fs = rs - fr * 3;
      const int lw7 = (dw + fs) & 7;  // (s*8+dw+fs)&7, s-independent
      const int recbase = (((dr + fr) * 58 + dw + fs) << 7);
#pragma unroll
      for (int cs = 0; cs < 4; ++cs) {
        bf16x8 a0 = *(const bf16x8*)(wpc + rs * (KK * CC) + cs * 16);
        bf16x8 a1 = *(const bf16x8*)(wpc + rs * (KK * CC) + cs * 16 + 32 * CC);
        const int ab = recbase + ((((cs << 1) + hi) ^ lw7) << 4);
#pragma unroll
        for (int si = 0; si < 4; ++si) {
          if (si < ns) {
            bf16x8 b = *(const bf16x8*)(xs + ab + (s0 + si) * 1024);
            acc[0][si] = __builtin_amdgcn_mfma_f32_32x32x16_bf16(a0, b, acc[0][si], 0, 0, 0);
            acc[1][si] = __builtin_amdgcn_mfma_f32_32x32x16_bf16(a1, b, acc[1][si], 0, 0, 0);
          }
        }
      }
    }
  }

  // ---- epilogue: C/D frag: col=lane&31 -> spatial, row=(r&3)+8*(r>>2)+4*hi ----
#pragma unroll
  for (int kf = 0; kf < 2; ++kf) {
#pragma unroll
    for (int si = 0; si < 4; ++si) {
      if (si < ns) {
        int s = s0 + si;
#pragma unroll
        for (int r = 0; r < 16; ++r) {
          int krow = k0 + kf * 32 + (r & 3) + ((r >> 2) << 3) + (hi << 2);
          out[(((size_t)n * KK + krow) * HH + (r0 + dr)) * WW + s * 8 + dw] =
              acc[kf][si][r];
        }
      }
    }
  }
}

extern "C" void kernel_launch(void* const* d_in, const int* in_sizes, int n_in,
                              void* d_out, int out_size, void* d_ws, size_t ws_size,
                              hipStream_t stream) {
  const float* x = (const float*)d_in[0];
  const float* kin = (const float*)d_in[1];
  float* out = (float*)d_out;
  unsigned short* wt = (unsigned short*)d_ws;  // 9*128*128 bf16 = 288 KB

  hipLaunchKernelGGL(wtrans_kernel, dim3(576), dim3(256), 0, stream, kin, wt);
  hipLaunchKernelGGL(conv_kernel, dim3(14, 16), dim3(256), 0, stream, x, wt, out);
}

// Round 2
// 37.066 us; speedup vs baseline: 1.8947x; 1.8947x over previous
//
#include <hip/hip_runtime.h>
#include <hip/hip_bf16.h>

typedef __attribute__((ext_vector_type(8))) short bf16x8;
typedef __attribute__((ext_vector_type(16))) float f32x16;
typedef __attribute__((ext_vector_type(4))) unsigned int u32x4;

#define CC 128
#define KK 128
#define HH 56
#define WW 56
#define HW (HH * WW)

__device__ __forceinline__ unsigned short f2bf(float f) {
  unsigned int u = __builtin_bit_cast(unsigned int, f);
  u += 0x7FFFu + ((u >> 16) & 1u);
  return (unsigned short)(u >> 16);
}

// K1: kernel (K,C,3,3) f32 -> wt2 in MFMA-A-fragment order, fully coalesced
// for the conv kernel's loads:
//   wt2[ (((m*4+cs)*2+kp)*2+kf)*512 + lane*8 + j ]
//   m = ch*9+rs (0..17), k = kp*64+kf*32+(lane&31), c = ch*64+cs*16+(lane>>5)*8+j
__global__ void wtrans_kernel(const float* __restrict__ kin,
                              unsigned short* __restrict__ wt2) {
  int idx = blockIdx.x * 256 + threadIdx.x;  // 0 .. 147455, exact
  int j = idx & 7;
  int l = (idx >> 3) & 63;
  int kf = (idx >> 9) & 1;
  int kp = (idx >> 10) & 1;
  int cs = (idx >> 11) & 3;
  int m = idx >> 13;  // 0..17
  int ch = (m >= 9) ? 1 : 0;
  int rs = m - ch * 9;
  int k = kp * 64 + kf * 32 + (l & 31);
  int c = ch * 64 + cs * 16 + (l >> 5) * 8 + j;
  wt2[idx] = f2bf(kin[(k * CC + c) * 9 + rs]);
}

// K2: direct 3x3 conv as implicit GEMM, bf16 MFMA 32x32x16.
// Block: 512 thr (8 waves). Output tile: 128 k x (4 rows x 56 w).
// Wave (kp, sh): k-range kp*64 (2 kfrags of 32), sfrags: sh<3 ? {2sh,2sh+1} : {6}.
// LDS: x staged [6 rows][58 cols][64 c] bf16 (43.5 KB), XOR-swizzled slots,
// two 64-channel phases. A double-buffered in registers, coalesced from wt2.
__global__ __launch_bounds__(512, 2) void conv_kernel(
    const float* __restrict__ x, const unsigned short* __restrict__ wt2,
    float* __restrict__ out) {
  __shared__ __align__(16) unsigned char xs[6 * 58 * 128];  // 43.5 KB

  const int tid = threadIdx.x;
  const int lane = tid & 63;
  const int wv = tid >> 6;  // 0..7
  const int bh = blockIdx.x;  // 0..13
  const int n = blockIdx.y;   // 0..15
  const int r0 = bh * 4;

  const int p = lane & 31;   // spatial position within fragment
  const int dr = p >> 3;     // row offset 0..3
  const int dw = p & 7;      // col offset 0..7
  const int hi = lane >> 5;  // k-dim half

  const int kp = wv >> 2;         // 0..1 : k-half
  const int sh = wv & 3;          // 0..3 : spatial quarter
  const int ns = (sh == 3) ? 1 : 2;
  const int s0 = sh * 2;

  f32x16 acc[2][2] = {};  // [kf][si]

  const int gw = lane - 1;  // input w for staged column `lane`
  const bool wok = (gw >= 0) && (gw < WW);

  // stage x[n][ch*64 .. +63][r0-1 .. r0+4][-1 .. 56] -> LDS bf16.
  // wave = one channel-oct (oct = wv), rows 0..5; lane = column. b128 writes.
  auto stage = [&](int ch) {
    const int oct = wv;
    const float* xb = x + ((size_t)n * CC + (ch * 64 + oct * 8)) * HW + gw;
#pragma unroll
    for (int lr = 0; lr < 6; ++lr) {
      const int gh = r0 - 1 + lr;
      const bool ok = wok && (gh >= 0) && (gh < HH);
      const float* xp = xb + gh * WW;
      unsigned int q0, q1, q2, q3;
      {
        float v0 = ok ? xp[0 * HW] : 0.f;
        float v1 = ok ? xp[1 * HW] : 0.f;
        float v2 = ok ? xp[2 * HW] : 0.f;
        float v3 = ok ? xp[3 * HW] : 0.f;
        float v4 = ok ? xp[4 * HW] : 0.f;
        float v5 = ok ? xp[5 * HW] : 0.f;
        float v6 = ok ? xp[6 * HW] : 0.f;
        float v7 = ok ? xp[7 * HW] : 0.f;
        q0 = (unsigned int)f2bf(v0) | ((unsigned int)f2bf(v1) << 16);
        q1 = (unsigned int)f2bf(v2) | ((unsigned int)f2bf(v3) << 16);
        q2 = (unsigned int)f2bf(v4) | ((unsigned int)f2bf(v5) << 16);
        q3 = (unsigned int)f2bf(v6) | ((unsigned int)f2bf(v7) << 16);
      }
      if (lane < 58) {
        const int rec = lr * 58 + lane;
        u32x4 qq = {q0, q1, q2, q3};
        *(u32x4*)(xs + (rec << 7) + ((oct ^ (lane & 7)) << 4)) = qq;
      }
    }
  };

  // coalesced A-fragment load; i = cs*2 + kf
  auto loadA = [&](int m, int i) -> bf16x8 {
    return *(const bf16x8*)(wt2 +
                            ((((m * 4 + (i >> 1)) * 2 + kp) * 2 + (i & 1)) << 9) +
                            (lane << 3));
  };

  stage(0);
  __syncthreads();

  bf16x8 ac[8], an[8];
#pragma unroll
  for (int i = 0; i < 8; ++i) ac[i] = loadA(0, i);

#pragma unroll 1
  for (int m = 0; m < 18; ++m) {
    if (m == 9) {
      __syncthreads();
      stage(1);
      __syncthreads();
    }
    const int mn = (m < 17) ? m + 1 : 17;
#pragma unroll
    for (int i = 0; i < 8; ++i) an[i] = loadA(mn, i);

    const int rs = (m >= 9) ? m - 9 : m;
    const int fr = (rs * 11) >> 5;  // rs/3 for 0..8
    const int fs = rs - fr * 3;
    const int lw7 = (dw + fs) & 7;
    const int rbase = ((dr + fr) * 58 + dw + fs) << 7;

#pragma unroll
    for (int cs = 0; cs < 4; ++cs) {
      const int sbase = rbase + ((((cs << 1) + hi) ^ lw7) << 4);
#pragma unroll
      for (int si = 0; si < 2; ++si) {
        if (si < ns) {
          bf16x8 b = *(const bf16x8*)(xs + sbase + (s0 + si) * 1024);
          acc[0][si] = __builtin_amdgcn_mfma_f32_32x32x16_bf16(ac[cs * 2 + 0], b,
                                                               acc[0][si], 0, 0, 0);
          acc[1][si] = __builtin_amdgcn_mfma_f32_32x32x16_bf16(ac[cs * 2 + 1], b,
                                                               acc[1][si], 0, 0, 0);
        }
      }
    }
#pragma unroll
    for (int i = 0; i < 8; ++i) ac[i] = an[i];
  }

  // epilogue: C/D frag: col=lane&31 -> spatial, row=(r&3)+8*(r>>2)+4*hi
#pragma unroll
  for (int kf = 0; kf < 2; ++kf) {
#pragma unroll
    for (int si = 0; si < 2; ++si) {
      if (si < ns) {
        const int s = s0 + si;
#pragma unroll
        for (int r = 0; r < 16; ++r) {
          const int krow = kp * 64 + kf * 32 + (r & 3) + ((r >> 2) << 3) + (hi << 2);
          out[(((size_t)n * KK + krow) * HH + (r0 + dr)) * WW + s * 8 + dw] =
              acc[kf][si][r];
        }
      }
    }
  }
}

extern "C" void kernel_launch(void* const* d_in, const int* in_sizes, int n_in,
                              void* d_out, int out_size, void* d_ws, size_t ws_size,
                              hipStream_t stream) {
  const float* x = (const float*)d_in[0];
  const float* kin = (const float*)d_in[1];
  float* out = (float*)d_out;
  unsigned short* wt2 = (unsigned short*)d_ws;  // 147456 bf16 = 288 KB

  hipLaunchKernelGGL(wtrans_kernel, dim3(576), dim3(256), 0, stream, kin, wt2);
  hipLaunchKernelGGL(conv_kernel, dim3(14, 16), dim3(512), 0, stream, x, wt2, out);
}